// Round 1
// baseline (467.710 us; speedup 1.0000x reference)
//
#include <hip/hip_runtime.h>
#include <hip/hip_bf16.h>

// Problem constants (fixed by reference)
#define N_NODES   16384
#define DEG       16
#define EDGES     262144          // N_NODES*DEG
#define ITEMS     278528          // EDGES + N_NODES (self loops)
#define HC        256             // HEADS*OUT_C
#define KDIM      16384           // 64 nodes * 256 feat
#define NDIM      4096            // 64 nodes * 64 feat
#define NEG_SLOPE 0.2f

typedef __attribute__((ext_vector_type(8))) short short8;   // 8 bf16
typedef __attribute__((ext_vector_type(4))) float floatx4;

static __device__ __forceinline__ unsigned short f2bf(float f) {
    unsigned int u = __float_as_uint(f);
    u += 0x7FFFu + ((u >> 16) & 1u);   // RNE
    return (unsigned short)(u >> 16);
}

// ---- mean(edge_attr) partial sums: 256 blocks x 1024 rows -----------------
__global__ __launch_bounds__(256) void k_ea_part(const float* __restrict__ ea,
                                                 float* __restrict__ part) {
    __shared__ float s[256];
    int b = blockIdx.x, t = threadIdx.x;
    int col = t & 15, r0 = t >> 4;
    const float* base = ea + (size_t)b * 1024 * 16;
    float acc = 0.f;
    for (int r = r0; r < 1024; r += 16) acc += base[r * 16 + col];
    s[t] = acc; __syncthreads();
    for (int off = 128; off >= 16; off >>= 1) {
        if (t < off) s[t] += s[t + off];
        __syncthreads();
    }
    if (t < 16) part[b * 16 + t] = s[t];
}

// ---- finish mean + ee_self = mean_ea @ W_e ---------------------------------
__global__ __launch_bounds__(256) void k_ea_finish(const float* __restrict__ part,
                                                   const float* __restrict__ We,
                                                   float* __restrict__ eeself) {
    __shared__ float mean[16];
    int t = threadIdx.x;
    if (t < 16) {
        float a = 0.f;
        for (int b = 0; b < 256; ++b) a += part[b * 16 + t];
        mean[t] = a * (1.f / (float)EDGES);
    }
    __syncthreads();
    float acc = 0.f;
    #pragma unroll
    for (int d = 0; d < 16; ++d) acc += mean[d] * We[d * 256 + t];
    eeself[t] = acc;
}

// ---- xl = x@W_l, xr = x@W_r : 16 nodes per block ---------------------------
__global__ __launch_bounds__(256) void k_xlr(const float* __restrict__ x,
                                             const float* __restrict__ Wl,
                                             const float* __restrict__ Wr,
                                             float* __restrict__ xl,
                                             float* __restrict__ xr) {
    __shared__ float xs[128][20];   // [k][node], padded for bank spread + f32x4 align
    int t = threadIdx.x;
    int n0 = blockIdx.x * 16;
    #pragma unroll
    for (int i = 0; i < 8; ++i) {
        int idx = t + i * 256;                 // idx = nn*128 + k
        xs[idx & 127][idx >> 7] = x[(size_t)n0 * 128 + idx];
    }
    __syncthreads();
    float al[16], ar[16];
    #pragma unroll
    for (int i = 0; i < 16; ++i) { al[i] = 0.f; ar[i] = 0.f; }
    for (int k = 0; k < 128; ++k) {
        float wl = Wl[k * 256 + t], wr = Wr[k * 256 + t];
        float xv[16];
        *(float4*)&xv[0]  = *(const float4*)&xs[k][0];
        *(float4*)&xv[4]  = *(const float4*)&xs[k][4];
        *(float4*)&xv[8]  = *(const float4*)&xs[k][8];
        *(float4*)&xv[12] = *(const float4*)&xs[k][12];
        #pragma unroll
        for (int i = 0; i < 16; ++i) { al[i] += xv[i] * wl; ar[i] += xv[i] * wr; }
    }
    #pragma unroll
    for (int i = 0; i < 16; ++i) {
        xl[(size_t)(n0 + i) * 256 + t] = al[i];
        xr[(size_t)(n0 + i) * 256 + t] = ar[i];
    }
}

// ---- transpose + bf16-convert lin_W: [16384][4096] f32 -> Wt[4096][16384] --
__global__ __launch_bounds__(256) void k_transpose(const float* __restrict__ W,
                                                   unsigned short* __restrict__ Wt) {
    __shared__ float tile[64][65];
    int t = threadIdx.x;
    int c = t & 63, r = t >> 6;
    int kt = blockIdx.x & 255, nt = blockIdx.x >> 8;
    size_t k0 = (size_t)kt * 64, n0 = (size_t)nt * 64;
    #pragma unroll
    for (int i = 0; i < 16; ++i) {
        int row = r + i * 4;
        tile[row][c] = W[(k0 + row) * 4096 + n0 + c];
    }
    __syncthreads();
    #pragma unroll
    for (int i = 0; i < 16; ++i) {
        int row = r + i * 4;
        Wt[(n0 + row) * 16384 + k0 + c] = f2bf(tile[c][row]);
    }
}

// ---- per-edge attention logits (incl. self-loops), one wave per edge ------
__global__ __launch_bounds__(256) void k_logits(const int* __restrict__ ei,
                                                const float* __restrict__ ea,
                                                const float* __restrict__ We,
                                                const float* __restrict__ att,
                                                const float* __restrict__ xl,
                                                const float* __restrict__ xr,
                                                const float* __restrict__ eeself,
                                                float* __restrict__ lgt) {
    int t = threadIdx.x;
    int lane = t & 63;
    int item = blockIdx.x * 4 + (t >> 6);
    int f = lane * 4;                     // 4 features, head = lane>>4
    int s, d;
    float eex, eey, eez, eew;
    if (item < EDGES) {
        s = ei[item];
        d = ei[EDGES + item];
        const float4* ea4 = (const float4*)(ea + (size_t)item * 16);
        float4 e0 = ea4[0], e1 = ea4[1], e2 = ea4[2], e3 = ea4[3];
        float eav[16] = {e0.x, e0.y, e0.z, e0.w, e1.x, e1.y, e1.z, e1.w,
                         e2.x, e2.y, e2.z, e2.w, e3.x, e3.y, e3.z, e3.w};
        eex = eey = eez = eew = 0.f;
        #pragma unroll
        for (int dd = 0; dd < 16; ++dd) {
            float4 w = *(const float4*)(We + dd * 256 + f);
            eex += eav[dd] * w.x; eey += eav[dd] * w.y;
            eez += eav[dd] * w.z; eew += eav[dd] * w.w;
        }
    } else {
        s = item - EDGES; d = s;
        float4 e = *(const float4*)(eeself + f);
        eex = e.x; eey = e.y; eez = e.z; eew = e.w;
    }
    float4 xlv = *(const float4*)(xl + (size_t)s * 256 + f);
    float4 xrv = *(const float4*)(xr + (size_t)d * 256 + f);
    float4 av  = *(const float4*)(att + f);
    float p = 0.f, v;
    v = xlv.x + xrv.x + eex; v = v > 0.f ? v : NEG_SLOPE * v; p += v * av.x;
    v = xlv.y + xrv.y + eey; v = v > 0.f ? v : NEG_SLOPE * v; p += v * av.y;
    v = xlv.z + xrv.z + eez; v = v > 0.f ? v : NEG_SLOPE * v; p += v * av.z;
    v = xlv.w + xrv.w + eew; v = v > 0.f ? v : NEG_SLOPE * v; p += v * av.w;
    p += __shfl_xor(p, 1);
    p += __shfl_xor(p, 2);
    p += __shfl_xor(p, 4);
    p += __shfl_xor(p, 8);
    if ((lane & 15) == 0) lgt[(size_t)item * 4 + (lane >> 4)] = p;
}

// ---- per-node softmax over 17 in-edges + weighted mean aggregation --------
__global__ __launch_bounds__(256) void k_node(const int* __restrict__ ei,
                                              const float* __restrict__ lgt,
                                              const float* __restrict__ xl,
                                              const float* __restrict__ bgat,
                                              unsigned short* __restrict__ hb) {
    __shared__ float lg[4][17];
    __shared__ float al[4][17];
    __shared__ int   srcs[17];
    int n = blockIdx.x, t = threadIdx.x;
    if (t < 17) srcs[t] = (t < 16) ? ei[n * 16 + t] : n;
    if (t < 68) {
        int h = t / 17, j = t % 17;
        int item = (j < 16) ? (n * 16 + j) : (EDGES + n);
        lg[h][j] = lgt[(size_t)item * 4 + h];
    }
    __syncthreads();
    if (t < 4) {
        float m = -1e30f;
        for (int j = 0; j < 17; ++j) m = fmaxf(m, lg[t][j]);
        float ssum = 0.f;
        for (int j = 0; j < 17; ++j) { float e = __expf(lg[t][j] - m); al[t][j] = e; ssum += e; }
        float inv = 1.f / ssum;
        for (int j = 0; j < 17; ++j) al[t][j] *= inv;
    }
    __syncthreads();
    int h = t >> 6;
    float acc = 0.f;
    #pragma unroll
    for (int j = 0; j < 17; ++j) acc += al[h][j] * xl[(size_t)srcs[j] * 256 + t];
    float val = acc * (1.f / 17.f) + bgat[t];
    hb[(size_t)n * 256 + t] = f2bf(val);
}

// ---- big GEMM: (256 x 16384) bf16 @ Wt^T -> partials[s][256][4096] ---------
__global__ __launch_bounds__(512) void k_gemm(const unsigned short* __restrict__ hb,
                                              const unsigned short* __restrict__ Wt,
                                              float* __restrict__ parts) {
    __shared__ unsigned short As[256][40];   // 256 rows(M) x 32 k, pad->40
    __shared__ unsigned short Bs[128][40];   // 128 rows(N) x 32 k, pad->40
    int t = threadIdx.x;
    int wave = t >> 6, lane = t & 63;
    int wm = wave >> 1, wn = wave & 1;       // 4 M-waves x 2 N-waves
    int n0 = blockIdx.x * 128;
    int s  = blockIdx.y;
    int kbase = s * 2048;
    const int l15 = lane & 15, lk = lane >> 4;

    floatx4 acc[4][4];
    #pragma unroll
    for (int i = 0; i < 4; ++i)
        #pragma unroll
        for (int j = 0; j < 4; ++j)
            acc[i][j] = (floatx4)(0.f);

    int arow = t >> 1, ahalf = t & 1;
    int brow = t >> 2, bq = t & 3;

    for (int kt = 0; kt < 2048; kt += 32) {
        int k0 = kbase + kt;
        __syncthreads();
        {   // stage A: 256x32 bf16
            const uint4* g = (const uint4*)(hb + (size_t)arow * KDIM + k0 + ahalf * 16);
            uint4 v0 = g[0], v1 = g[1];
            *(uint4*)&As[arow][ahalf * 16]     = v0;
            *(uint4*)&As[arow][ahalf * 16 + 8] = v1;
        }
        {   // stage B: 128x32 bf16
            uint4 v = *(const uint4*)(Wt + (size_t)(n0 + brow) * KDIM + k0 + bq * 8);
            *(uint4*)&Bs[brow][bq * 8] = v;
        }
        __syncthreads();
        short8 a[4], b[4];
        #pragma unroll
        for (int mi = 0; mi < 4; ++mi)
            a[mi] = *(const short8*)&As[wm * 64 + mi * 16 + l15][lk * 8];
        #pragma unroll
        for (int ni = 0; ni < 4; ++ni)
            b[ni] = *(const short8*)&Bs[wn * 64 + ni * 16 + l15][lk * 8];
        #pragma unroll
        for (int mi = 0; mi < 4; ++mi)
            #pragma unroll
            for (int ni = 0; ni < 4; ++ni)
                acc[mi][ni] = __builtin_amdgcn_mfma_f32_16x16x32_bf16(a[mi], b[ni], acc[mi][ni], 0, 0, 0);
    }

    float* dst = parts + (size_t)s * (256 * 4096);
    #pragma unroll
    for (int mi = 0; mi < 4; ++mi) {
        #pragma unroll
        for (int ni = 0; ni < 4; ++ni) {
            int col = n0 + wn * 64 + ni * 16 + l15;
            #pragma unroll
            for (int r = 0; r < 4; ++r) {
                int row = wm * 64 + mi * 16 + lk * 4 + r;
                dst[(size_t)row * 4096 + col] = acc[mi][ni][r];
            }
        }
    }
}

// ---- reduce partials + bias -> d_out ---------------------------------------
__global__ __launch_bounds__(256) void k_reduce(const float* __restrict__ parts,
                                                const float* __restrict__ linb,
                                                float* __restrict__ out) {
    int idx = blockIdx.x * 256 + threadIdx.x;
    float v = linb[idx & 4095];
    #pragma unroll
    for (int s = 0; s < 8; ++s) v += parts[(size_t)s * (256 * 4096) + idx];
    out[idx] = v;
}

extern "C" void kernel_launch(void* const* d_in, const int* in_sizes, int n_in,
                              void* d_out, int out_size, void* d_ws, size_t ws_size,
                              hipStream_t stream) {
    (void)in_sizes; (void)n_in; (void)out_size; (void)ws_size;
    const float* x   = (const float*)d_in[0];
    const int*   ei  = (const int*)d_in[1];
    const float* ea  = (const float*)d_in[2];
    /* d_in[3] = batch (unused, fixed layout) */
    const float* Wl  = (const float*)d_in[4];
    const float* Wr  = (const float*)d_in[5];
    const float* We  = (const float*)d_in[6];
    const float* att = (const float*)d_in[7];
    const float* bg  = (const float*)d_in[8];
    const float* W   = (const float*)d_in[9];
    const float* lb  = (const float*)d_in[10];
    float* out = (float*)d_out;

    char* p = (char*)d_ws;
    unsigned short* Wt  = (unsigned short*)p; p += (size_t)134217728;  // 4096x16384 bf16
    float* xl           = (float*)p;          p += 16777216;           // 16384x256 f32
    float* xr           = (float*)p;          p += 16777216;
    unsigned short* hb  = (unsigned short*)p; p += 8388608;            // 16384x256 bf16
    float* lgbuf        = (float*)p;          p += 4456448;            // 278528x4 f32
    float* parts        = (float*)p;          p += 33554432;           // 8x256x4096 f32
    float* eapart       = (float*)p;          p += 16384;              // 256x16
    float* eeself       = (float*)p;          p += 1024;               // 256

    k_ea_part  <<<256,   256, 0, stream>>>(ea, eapart);
    k_ea_finish<<<1,     256, 0, stream>>>(eapart, We, eeself);
    k_xlr      <<<1024,  256, 0, stream>>>(x, Wl, Wr, xl, xr);
    k_transpose<<<16384, 256, 0, stream>>>(W, Wt);
    k_logits   <<<69632, 256, 0, stream>>>(ei, ea, We, att, xl, xr, eeself, lgbuf);
    k_node     <<<16384, 256, 0, stream>>>(ei, lgbuf, xl, bg, hb);
    k_gemm     <<<dim3(32, 8), 512, 0, stream>>>(hb, Wt, parts);
    k_reduce   <<<4096,  256, 0, stream>>>(parts, lb, out);
}

// Round 2
// 364.594 us; speedup vs baseline: 1.2828x; 1.2828x over previous
//
#include <hip/hip_runtime.h>
#include <hip/hip_bf16.h>

// Problem constants (fixed by reference)
#define N_NODES   16384
#define DEG       16
#define EDGES     262144          // N_NODES*DEG
#define ITEMS     278528          // EDGES + N_NODES (self loops)
#define HC        256             // HEADS*OUT_C
#define KDIM      16384           // 64 nodes * 256 feat
#define NDIM      4096            // 64 nodes * 64 feat
#define NEG_SLOPE 0.2f

typedef __attribute__((ext_vector_type(8))) short short8;   // 8 bf16
typedef __attribute__((ext_vector_type(4))) float floatx4;

static __device__ __forceinline__ unsigned short f2bf(float f) {
    unsigned int u = __float_as_uint(f);
    u += 0x7FFFu + ((u >> 16) & 1u);   // RNE
    return (unsigned short)(u >> 16);
}

// ---- mean(edge_attr) partial sums: 256 blocks x 1024 rows -----------------
__global__ __launch_bounds__(256) void k_ea_part(const float* __restrict__ ea,
                                                 float* __restrict__ part) {
    __shared__ float s[256];
    int b = blockIdx.x, t = threadIdx.x;
    int col = t & 15, r0 = t >> 4;
    const float* base = ea + (size_t)b * 1024 * 16;
    float acc = 0.f;
    for (int r = r0; r < 1024; r += 16) acc += base[r * 16 + col];
    s[t] = acc; __syncthreads();
    for (int off = 128; off >= 16; off >>= 1) {
        if (t < off) s[t] += s[t + off];
        __syncthreads();
    }
    if (t < 16) part[b * 16 + t] = s[t];
}

// ---- finish mean + ee_self = mean_ea @ W_e ---------------------------------
__global__ __launch_bounds__(256) void k_ea_finish(const float* __restrict__ part,
                                                   const float* __restrict__ We,
                                                   float* __restrict__ eeself) {
    __shared__ float mean[16];
    int t = threadIdx.x;
    if (t < 16) {
        float a = 0.f;
        for (int b = 0; b < 256; ++b) a += part[b * 16 + t];
        mean[t] = a * (1.f / (float)EDGES);
    }
    __syncthreads();
    float acc = 0.f;
    #pragma unroll
    for (int d = 0; d < 16; ++d) acc += mean[d] * We[d * 256 + t];
    eeself[t] = acc;
}

// ---- xl = x@W_l, xr = x@W_r : 16 nodes per block ---------------------------
__global__ __launch_bounds__(256) void k_xlr(const float* __restrict__ x,
                                             const float* __restrict__ Wl,
                                             const float* __restrict__ Wr,
                                             float* __restrict__ xl,
                                             float* __restrict__ xr) {
    __shared__ float xs[128][20];   // [k][node], padded
    int t = threadIdx.x;
    int n0 = blockIdx.x * 16;
    #pragma unroll
    for (int i = 0; i < 8; ++i) {
        int idx = t + i * 256;                 // idx = nn*128 + k
        xs[idx & 127][idx >> 7] = x[(size_t)n0 * 128 + idx];
    }
    __syncthreads();
    float al[16], ar[16];
    #pragma unroll
    for (int i = 0; i < 16; ++i) { al[i] = 0.f; ar[i] = 0.f; }
    for (int k = 0; k < 128; ++k) {
        float wl = Wl[k * 256 + t], wr = Wr[k * 256 + t];
        float xv[16];
        *(float4*)&xv[0]  = *(const float4*)&xs[k][0];
        *(float4*)&xv[4]  = *(const float4*)&xs[k][4];
        *(float4*)&xv[8]  = *(const float4*)&xs[k][8];
        *(float4*)&xv[12] = *(const float4*)&xs[k][12];
        #pragma unroll
        for (int i = 0; i < 16; ++i) { al[i] += xv[i] * wl; ar[i] += xv[i] * wr; }
    }
    #pragma unroll
    for (int i = 0; i < 16; ++i) {
        xl[(size_t)(n0 + i) * 256 + t] = al[i];
        xr[(size_t)(n0 + i) * 256 + t] = ar[i];
    }
}

// ---- transpose + bf16-convert lin_W: [16384][4096] f32 -> Wt[4096][16384] --
__global__ __launch_bounds__(256) void k_transpose(const float* __restrict__ W,
                                                   unsigned short* __restrict__ Wt) {
    __shared__ float tile[64][65];
    int t = threadIdx.x;
    int c = t & 63, r = t >> 6;
    int kt = blockIdx.x & 255, nt = blockIdx.x >> 8;
    size_t k0 = (size_t)kt * 64, n0 = (size_t)nt * 64;
    #pragma unroll
    for (int i = 0; i < 16; ++i) {
        int row = r + i * 4;
        tile[row][c] = W[(k0 + row) * 4096 + n0 + c];
    }
    __syncthreads();
    #pragma unroll
    for (int i = 0; i < 16; ++i) {
        int row = r + i * 4;
        Wt[(n0 + row) * 16384 + k0 + c] = f2bf(tile[c][row]);
    }
}

// ---- fused GAT attention: logits + segment softmax + mean aggregation ------
// grid: 1024 blocks = (graph g, head h); block = 256 threads = 4 waves
__global__ __launch_bounds__(256) void k_attn(const int* __restrict__ ei,
                                              const float* __restrict__ ea,
                                              const float* __restrict__ eeself,
                                              const float* __restrict__ att,
                                              const float* __restrict__ We,
                                              const float* __restrict__ xl,
                                              const float* __restrict__ xr,
                                              const float* __restrict__ bg,
                                              unsigned short* __restrict__ hb) {
    __shared__ float xlS[64][65];    // head slice of xl, pad 65 for gather spread
    __shared__ float xrS[64][65];
    __shared__ float WeS[16 * 64];   // W_e head slice
    __shared__ float attS[64];
    __shared__ float lgS[1088];      // logits -> alpha (in place)
    __shared__ int   srcS[1024];     // local src per edge

    int t = threadIdx.x;
    int g = blockIdx.x >> 2, h = blockIdx.x & 3;
    int hc0 = h * 64;

    {   // stage xl/xr head slices: 64 nodes x 64 feats
        int n = t >> 2, q = t & 3;
        const float* xlp = xl + ((size_t)(g * 64 + n)) * 256 + hc0 + q * 16;
        const float* xrp = xr + ((size_t)(g * 64 + n)) * 256 + hc0 + q * 16;
        #pragma unroll
        for (int i = 0; i < 4; ++i) {
            *(float4*)&xlS[n][q * 16 + i * 4] = *(const float4*)(xlp + i * 4);
            *(float4*)&xrS[n][q * 16 + i * 4] = *(const float4*)(xrp + i * 4);
        }
    }
    {   // stage We head slice
        int dd0 = t >> 6, c = t & 63;
        #pragma unroll
        for (int i = 0; i < 4; ++i)
            WeS[(dd0 + i * 4) * 64 + c] = We[(dd0 + i * 4) * 256 + hc0 + c];
    }
    if (t < 64) attS[t] = att[hc0 + t];
    __syncthreads();

    int wave = t >> 6, lane = t & 63;

    // ---- logits: lane = item, batches of 64 items ----
    for (int b = wave; b < 17; b += 4) {
        asm volatile("" ::: "memory");   // block cross-batch hoisting of LDS reads
        bool isself = (b == 16);
        int srcl, dstl;
        float eav[16];
        if (!isself) {
            int e = b * 64 + lane;
            srcl = ei[g * 1024 + e] & 63;
            dstl = e >> 4;
            srcS[e] = srcl;
            const float4* ep = (const float4*)(ea + ((size_t)g * 1024 + e) * 16);
            float4 e0 = ep[0], e1 = ep[1], e2 = ep[2], e3 = ep[3];
            eav[0]=e0.x; eav[1]=e0.y; eav[2]=e0.z; eav[3]=e0.w;
            eav[4]=e1.x; eav[5]=e1.y; eav[6]=e1.z; eav[7]=e1.w;
            eav[8]=e2.x; eav[9]=e2.y; eav[10]=e2.z; eav[11]=e2.w;
            eav[12]=e3.x; eav[13]=e3.y; eav[14]=e3.z; eav[15]=e3.w;
        } else {
            srcl = lane; dstl = lane;
        }
        float s0 = 0.f, s1 = 0.f, s2 = 0.f, s3 = 0.f;
        #pragma unroll
        for (int half = 0; half < 2; ++half) {
            float ee[32];
            if (!isself) {
                #pragma unroll
                for (int c = 0; c < 32; ++c) ee[c] = 0.f;
                #pragma unroll
                for (int dd = 0; dd < 16; ++dd) {
                    float ev = eav[dd];
                    #pragma unroll
                    for (int c = 0; c < 32; ++c)
                        ee[c] += ev * WeS[dd * 64 + half * 32 + c];
                }
            } else {
                #pragma unroll
                for (int c = 0; c < 32; ++c) ee[c] = eeself[hc0 + half * 32 + c];
            }
            #pragma unroll
            for (int c = 0; c < 32; ++c) {
                int cc = half * 32 + c;
                float f = xlS[srcl][cc] + xrS[dstl][cc] + ee[c];
                f = f > 0.f ? f : NEG_SLOPE * f;
                float p = f * attS[cc];
                if ((c & 3) == 0) s0 += p;
                else if ((c & 3) == 1) s1 += p;
                else if ((c & 3) == 2) s2 += p;
                else s3 += p;
            }
        }
        float lsum = (s0 + s1) + (s2 + s3);
        if (isself) lgS[1024 + lane] = lsum;
        else        lgS[b * 64 + lane] = lsum;
    }
    __syncthreads();

    // ---- segment softmax per dst node (17 entries each), fold 1/17 ----
    if (t < 64) {
        float lg[17];
        #pragma unroll
        for (int j = 0; j < 16; ++j) lg[j] = lgS[t * 16 + j];
        lg[16] = lgS[1024 + t];
        float m = lg[0];
        #pragma unroll
        for (int j = 1; j < 17; ++j) m = fmaxf(m, lg[j]);
        float ex[17], ssum = 0.f;
        #pragma unroll
        for (int j = 0; j < 17; ++j) { ex[j] = __expf(lg[j] - m); ssum += ex[j]; }
        float inv = 1.f / (17.f * ssum);
        #pragma unroll
        for (int j = 0; j < 16; ++j) lgS[t * 16 + j] = ex[j] * inv;
        lgS[1024 + t] = ex[16] * inv;
    }
    __syncthreads();

    // ---- aggregation: lane = feature c, 16 nodes per wave ----
    {
        int c = lane;
        float bgv = bg[hc0 + c];
        for (int n = wave * 16; n < wave * 16 + 16; ++n) {
            float a0 = lgS[1024 + n] * xlS[n][c];
            float a1 = 0.f;
            #pragma unroll
            for (int j = 0; j < 16; j += 2) {
                a0 += lgS[n * 16 + j]     * xlS[srcS[n * 16 + j]][c];
                a1 += lgS[n * 16 + j + 1] * xlS[srcS[n * 16 + j + 1]][c];
            }
            float val = a0 + a1 + bgv;
            hb[((size_t)(g * 64 + n)) * 256 + hc0 + c] = f2bf(val);
        }
    }
}

// ---- big GEMM: (256 x 16384) bf16 @ Wt^T -> partials[s][256][4096] ---------
__global__ __launch_bounds__(512) void k_gemm(const unsigned short* __restrict__ hb,
                                              const unsigned short* __restrict__ Wt,
                                              float* __restrict__ parts) {
    __shared__ unsigned short As[256][40];   // 256 rows(M) x 32 k, pad->40
    __shared__ unsigned short Bs[128][40];   // 128 rows(N) x 32 k, pad->40
    int t = threadIdx.x;
    int wave = t >> 6, lane = t & 63;
    int wm = wave >> 1, wn = wave & 1;       // 4 M-waves x 2 N-waves
    int n0 = blockIdx.x * 128;
    int s  = blockIdx.y;
    int kbase = s * 2048;
    const int l15 = lane & 15, lk = lane >> 4;

    floatx4 acc[4][4];
    #pragma unroll
    for (int i = 0; i < 4; ++i)
        #pragma unroll
        for (int j = 0; j < 4; ++j)
            acc[i][j] = (floatx4)(0.f);

    int arow = t >> 1, ahalf = t & 1;
    int brow = t >> 2, bq = t & 3;

    for (int kt = 0; kt < 2048; kt += 32) {
        int k0 = kbase + kt;
        __syncthreads();
        {   // stage A: 256x32 bf16
            const uint4* g = (const uint4*)(hb + (size_t)arow * KDIM + k0 + ahalf * 16);
            uint4 v0 = g[0], v1 = g[1];
            *(uint4*)&As[arow][ahalf * 16]     = v0;
            *(uint4*)&As[arow][ahalf * 16 + 8] = v1;
        }
        {   // stage B: 128x32 bf16
            uint4 v = *(const uint4*)(Wt + (size_t)(n0 + brow) * KDIM + k0 + bq * 8);
            *(uint4*)&Bs[brow][bq * 8] = v;
        }
        __syncthreads();
        short8 a[4], b[4];
        #pragma unroll
        for (int mi = 0; mi < 4; ++mi)
            a[mi] = *(const short8*)&As[wm * 64 + mi * 16 + l15][lk * 8];
        #pragma unroll
        for (int ni = 0; ni < 4; ++ni)
            b[ni] = *(const short8*)&Bs[wn * 64 + ni * 16 + l15][lk * 8];
        #pragma unroll
        for (int mi = 0; mi < 4; ++mi)
            #pragma unroll
            for (int ni = 0; ni < 4; ++ni)
                acc[mi][ni] = __builtin_amdgcn_mfma_f32_16x16x32_bf16(a[mi], b[ni], acc[mi][ni], 0, 0, 0);
    }

    float* dst = parts + (size_t)s * (256 * 4096);
    #pragma unroll
    for (int mi = 0; mi < 4; ++mi) {
        #pragma unroll
        for (int ni = 0; ni < 4; ++ni) {
            int col = n0 + wn * 64 + ni * 16 + l15;
            #pragma unroll
            for (int r = 0; r < 4; ++r) {
                int row = wm * 64 + mi * 16 + lk * 4 + r;
                dst[(size_t)row * 4096 + col] = acc[mi][ni][r];
            }
        }
    }
}

// ---- reduce partials + bias -> d_out ---------------------------------------
__global__ __launch_bounds__(256) void k_reduce(const float* __restrict__ parts,
                                                const float* __restrict__ linb,
                                                float* __restrict__ out) {
    int idx = blockIdx.x * 256 + threadIdx.x;
    float v = linb[idx & 4095];
    #pragma unroll
    for (int s = 0; s < 8; ++s) v += parts[(size_t)s * (256 * 4096) + idx];
    out[idx] = v;
}

extern "C" void kernel_launch(void* const* d_in, const int* in_sizes, int n_in,
                              void* d_out, int out_size, void* d_ws, size_t ws_size,
                              hipStream_t stream) {
    (void)in_sizes; (void)n_in; (void)out_size; (void)ws_size;
    const float* x   = (const float*)d_in[0];
    const int*   ei  = (const int*)d_in[1];
    const float* ea  = (const float*)d_in[2];
    /* d_in[3] = batch (unused, fixed layout) */
    const float* Wl  = (const float*)d_in[4];
    const float* Wr  = (const float*)d_in[5];
    const float* We  = (const float*)d_in[6];
    const float* att = (const float*)d_in[7];
    const float* bg  = (const float*)d_in[8];
    const float* W   = (const float*)d_in[9];
    const float* lb  = (const float*)d_in[10];
    float* out = (float*)d_out;

    char* p = (char*)d_ws;
    unsigned short* Wt  = (unsigned short*)p; p += (size_t)134217728;  // 4096x16384 bf16
    float* xl           = (float*)p;          p += 16777216;           // 16384x256 f32
    float* xr           = (float*)p;          p += 16777216;
    unsigned short* hb  = (unsigned short*)p; p += 8388608;            // 16384x256 bf16
    float* lgbuf        = (float*)p;          p += 4456448;            // (unused now)
    float* parts        = (float*)p;          p += 33554432;           // 8x256x4096 f32
    float* eapart       = (float*)p;          p += 16384;              // 256x16
    float* eeself       = (float*)p;          p += 1024;               // 256
    (void)lgbuf;

    k_ea_part  <<<256,   256, 0, stream>>>(ea, eapart);
    k_ea_finish<<<1,     256, 0, stream>>>(eapart, We, eeself);
    k_xlr      <<<1024,  256, 0, stream>>>(x, Wl, Wr, xl, xr);
    k_transpose<<<16384, 256, 0, stream>>>(W, Wt);
    k_attn     <<<1024,  256, 0, stream>>>(ei, ea, eeself, att, We, xl, xr, bg, hb);
    k_gemm     <<<dim3(32, 8), 512, 0, stream>>>(hb, Wt, parts);
    k_reduce   <<<4096,  256, 0, stream>>>(parts, lb, out);
}

// Round 3
// 263.972 us; speedup vs baseline: 1.7718x; 1.3812x over previous
//
#include <hip/hip_runtime.h>
#include <hip/hip_bf16.h>

// Problem constants (fixed by reference)
#define N_NODES   16384
#define DEG       16
#define EDGES     262144          // N_NODES*DEG
#define HC        256             // HEADS*OUT_C
#define KDIM      16384           // 64 nodes * 256 feat
#define NEG_SLOPE 0.2f

typedef __attribute__((ext_vector_type(8))) short short8;   // 8 bf16
typedef __attribute__((ext_vector_type(4))) float floatx4;

static __device__ __forceinline__ unsigned short f2bf(float f) {
    unsigned int u = __float_as_uint(f);
    u += 0x7FFFu + ((u >> 16) & 1u);   // RNE
    return (unsigned short)(u >> 16);
}
static __device__ __forceinline__ unsigned int packbf2(float lo, float hi) {
    return ((unsigned int)f2bf(hi) << 16) | f2bf(lo);
}

// ---- mean(edge_attr) partial sums: 256 blocks x 1024 rows -----------------
__global__ __launch_bounds__(256) void k_ea_part(const float* __restrict__ ea,
                                                 float* __restrict__ part) {
    __shared__ float s[256];
    int b = blockIdx.x, t = threadIdx.x;
    int col = t & 15, r0 = t >> 4;
    const float* base = ea + (size_t)b * 1024 * 16;
    float acc = 0.f;
    for (int r = r0; r < 1024; r += 16) acc += base[r * 16 + col];
    s[t] = acc; __syncthreads();
    for (int off = 128; off >= 16; off >>= 1) {
        if (t < off) s[t] += s[t + off];
        __syncthreads();
    }
    if (t < 16) part[b * 16 + t] = s[t];
}

// ---- finish mean + ee_self = mean_ea @ W_e ---------------------------------
__global__ __launch_bounds__(256) void k_ea_finish(const float* __restrict__ part,
                                                   const float* __restrict__ We,
                                                   float* __restrict__ eeself) {
    __shared__ float mean[16];
    int t = threadIdx.x;
    if (t < 16) {
        float a = 0.f;
        for (int b = 0; b < 256; ++b) a += part[b * 16 + t];
        mean[t] = a * (1.f / (float)EDGES);
    }
    __syncthreads();
    float acc = 0.f;
    #pragma unroll
    for (int d = 0; d < 16; ++d) acc += mean[d] * We[d * 256 + t];
    eeself[t] = acc;
}

// ---- xl = x@W_l, xr = x@W_r : 16 nodes per block ---------------------------
__global__ __launch_bounds__(256) void k_xlr(const float* __restrict__ x,
                                             const float* __restrict__ Wl,
                                             const float* __restrict__ Wr,
                                             float* __restrict__ xl,
                                             float* __restrict__ xr) {
    __shared__ float xs[128][20];
    int t = threadIdx.x;
    int n0 = blockIdx.x * 16;
    #pragma unroll
    for (int i = 0; i < 8; ++i) {
        int idx = t + i * 256;                 // idx = nn*128 + k
        xs[idx & 127][idx >> 7] = x[(size_t)n0 * 128 + idx];
    }
    __syncthreads();
    float al[16], ar[16];
    #pragma unroll
    for (int i = 0; i < 16; ++i) { al[i] = 0.f; ar[i] = 0.f; }
    for (int k = 0; k < 128; ++k) {
        float wl = Wl[k * 256 + t], wr = Wr[k * 256 + t];
        float xv[16];
        *(float4*)&xv[0]  = *(const float4*)&xs[k][0];
        *(float4*)&xv[4]  = *(const float4*)&xs[k][4];
        *(float4*)&xv[8]  = *(const float4*)&xs[k][8];
        *(float4*)&xv[12] = *(const float4*)&xs[k][12];
        #pragma unroll
        for (int i = 0; i < 16; ++i) { al[i] += xv[i] * wl; ar[i] += xv[i] * wr; }
    }
    #pragma unroll
    for (int i = 0; i < 16; ++i) {
        xl[(size_t)(n0 + i) * 256 + t] = al[i];
        xr[(size_t)(n0 + i) * 256 + t] = ar[i];
    }
}

// ---- fused GAT attention v3: MFMA ee + in-layout logits + softmax + agg ----
// grid: 1024 blocks = (graph g, head h); block = 256 threads = 4 waves
__global__ __launch_bounds__(256) void k_attn(const int* __restrict__ ei,
                                              const float* __restrict__ ea,
                                              const float* __restrict__ eeself,
                                              const float* __restrict__ att,
                                              const float* __restrict__ We,
                                              const float* __restrict__ xl,
                                              const float* __restrict__ xr,
                                              const float* __restrict__ bg,
                                              unsigned short* __restrict__ hb) {
    __shared__ float xlS[64][65];
    __shared__ float xrS[64][65];
    __shared__ float lgS[1088];      // 1024 edge logits + 64 self
    __shared__ int   srcS[1024];

    int t = threadIdx.x;
    int g = blockIdx.x >> 2, h = blockIdx.x & 3;
    int hc0 = h * 64;

    {   // stage xl/xr head slices: 64 nodes x 64 feats
        int n = t >> 2, q4 = t & 3;
        const float* xlp = xl + ((size_t)(g * 64 + n)) * 256 + hc0 + q4 * 16;
        const float* xrp = xr + ((size_t)(g * 64 + n)) * 256 + hc0 + q4 * 16;
        #pragma unroll
        for (int i = 0; i < 4; ++i) {
            *(float4*)&xlS[n][q4 * 16 + i * 4] = *(const float4*)(xlp + i * 4);
            *(float4*)&xrS[n][q4 * 16 + i * 4] = *(const float4*)(xrp + i * 4);
        }
    }
    {   // stage local src indices for all 1024 edges
        int4 v = *(const int4*)(ei + (size_t)g * 1024 + t * 4);
        srcS[t * 4 + 0] = v.x & 63;
        srcS[t * 4 + 1] = v.y & 63;
        srcS[t * 4 + 2] = v.z & 63;
        srcS[t * 4 + 3] = v.w & 63;
    }

    int wave = t >> 6, lane = t & 63;
    int q = lane >> 4, l15 = lane & 15;

    // B-frags: We head-slice held in registers for the whole block.
    // wf[nt] elem j = We[k=q*8+j][hc0 + nt*16 + l15]; k>=16 lanes (q>=2) zero.
    short8 wf[4];
    float  attv[4];
    #pragma unroll
    for (int nt = 0; nt < 4; ++nt) {
        attv[nt] = att[hc0 + nt * 16 + l15];
        if (q < 2) {
            const float* wp = We + (size_t)(q * 8) * 256 + hc0 + nt * 16 + l15;
            float w0 = wp[0*256], w1 = wp[1*256], w2 = wp[2*256], w3 = wp[3*256];
            float w4 = wp[4*256], w5 = wp[5*256], w6 = wp[6*256], w7 = wp[7*256];
            union { unsigned int u[4]; short8 v; } bb;
            bb.u[0] = packbf2(w0, w1);
            bb.u[1] = packbf2(w2, w3);
            bb.u[2] = packbf2(w4, w5);
            bb.u[3] = packbf2(w6, w7);
            wf[nt] = bb.v;
        } else {
            wf[nt] = (short8)0;
        }
    }
    __syncthreads();

    // ---- edge batches: 16 batches of 64 edges, waves independent ----
    for (int b = wave; b < 16; b += 4) {
        // A-frags: ea rows for 64 items; af[mt] elem j = ea[item][q*8+j], q>=2 zero
        short8 af[4];
        #pragma unroll
        for (int mt = 0; mt < 4; ++mt) {
            if (q < 2) {
                const float* ep = ea + ((size_t)(g * 1024 + b * 64 + mt * 16 + l15)) * 16 + q * 8;
                float4 v0 = *(const float4*)ep;
                float4 v1 = *(const float4*)(ep + 4);
                union { unsigned int u[4]; short8 v; } bb;
                bb.u[0] = packbf2(v0.x, v0.y);
                bb.u[1] = packbf2(v0.z, v0.w);
                bb.u[2] = packbf2(v1.x, v1.y);
                bb.u[3] = packbf2(v1.z, v1.w);
                af[mt] = bb.v;
            } else {
                af[mt] = (short8)0;
            }
        }
        // ee = ea @ We : C[item][c], item = mt*16 + q*4 + r, c = nt*16 + l15
        floatx4 acc[4][4];
        #pragma unroll
        for (int mt = 0; mt < 4; ++mt)
            #pragma unroll
            for (int nt = 0; nt < 4; ++nt)
                acc[mt][nt] = __builtin_amdgcn_mfma_f32_16x16x32_bf16(af[mt], wf[nt], (floatx4)(0.f), 0, 0, 0);

        // src rows per (mt, r) — broadcast LDS reads
        int srcr[4][4];
        #pragma unroll
        for (int mt = 0; mt < 4; ++mt)
            #pragma unroll
            for (int r = 0; r < 4; ++r)
                srcr[mt][r] = srcS[b * 64 + mt * 16 + q * 4 + r];

        #pragma unroll
        for (int mt = 0; mt < 4; ++mt) {
            float lsum[4] = {0.f, 0.f, 0.f, 0.f};
            #pragma unroll
            for (int nt = 0; nt < 4; ++nt) {
                float xrv = xrS[b * 4 + mt][nt * 16 + l15];   // dst uniform per mt
                #pragma unroll
                for (int r = 0; r < 4; ++r) {
                    float f = acc[mt][nt][r] + xlS[srcr[mt][r]][nt * 16 + l15] + xrv;
                    f = fmaxf(f, NEG_SLOPE * f);              // leaky_relu (slope<1)
                    lsum[r] += f * attv[nt];
                }
            }
            #pragma unroll
            for (int r = 0; r < 4; ++r) {
                float v = lsum[r];
                v += __shfl_xor(v, 1);
                v += __shfl_xor(v, 2);
                v += __shfl_xor(v, 4);
                v += __shfl_xor(v, 8);
                if (l15 == 0) lgS[b * 64 + mt * 16 + q * 4 + r] = v;
            }
        }
    }

    // ---- self-loop batch: 64 items split across 4 waves (16 each) ----
    {
        int n = wave * 16 + l15;                 // item (node)
        float sum = 0.f;
        const float* eep = eeself + hc0 + q * 16;
        const float* ap  = att + hc0 + q * 16;
        #pragma unroll
        for (int i = 0; i < 4; ++i) {
            float4 ev = *(const float4*)(eep + i * 4);
            float4 av = *(const float4*)(ap + i * 4);
            #pragma unroll
            for (int j = 0; j < 4; ++j) {
                int c = q * 16 + i * 4 + j;
                float e = (j == 0) ? ev.x : (j == 1) ? ev.y : (j == 2) ? ev.z : ev.w;
                float a = (j == 0) ? av.x : (j == 1) ? av.y : (j == 2) ? av.z : av.w;
                float f = xlS[n][c] + xrS[n][c] + e;
                f = fmaxf(f, NEG_SLOPE * f);
                sum += f * a;
            }
        }
        sum += __shfl_xor(sum, 16);
        sum += __shfl_xor(sum, 32);
        if (q == 0) lgS[1024 + n] = sum;
    }
    __syncthreads();

    // ---- segment softmax per dst node (17 entries), fold 1/17 ----
    if (t < 64) {
        float lg[17];
        #pragma unroll
        for (int j = 0; j < 16; ++j) lg[j] = lgS[t * 16 + j];
        lg[16] = lgS[1024 + t];
        float m = lg[0];
        #pragma unroll
        for (int j = 1; j < 17; ++j) m = fmaxf(m, lg[j]);
        float ex[17], ssum = 0.f;
        #pragma unroll
        for (int j = 0; j < 17; ++j) { ex[j] = __expf(lg[j] - m); ssum += ex[j]; }
        float inv = 1.f / (17.f * ssum);
        #pragma unroll
        for (int j = 0; j < 16; ++j) lgS[t * 16 + j] = ex[j] * inv;
        lgS[1024 + t] = ex[16] * inv;
    }
    __syncthreads();

    // ---- aggregation: lane = feature c, 16 nodes per wave ----
    {
        int c = lane;
        float bgv = bg[hc0 + c];
        for (int n = wave * 16; n < wave * 16 + 16; ++n) {
            float a0 = lgS[1024 + n] * xlS[n][c];
            float a1 = 0.f;
            #pragma unroll
            for (int j = 0; j < 16; j += 2) {
                a0 += lgS[n * 16 + j]     * xlS[srcS[n * 16 + j]][c];
                a1 += lgS[n * 16 + j + 1] * xlS[srcS[n * 16 + j + 1]][c];
            }
            float val = a0 + a1 + bgv;
            hb[((size_t)(g * 64 + n)) * 256 + hc0 + c] = f2bf(val);
        }
    }
}

// ---- big GEMM, W read directly (f32, K-major) with fused transpose+cvt -----
// (256 x 16384) bf16 @ W[16384 x 4096] -> partials[s][256][4096]
__global__ __launch_bounds__(512) void k_gemm(const unsigned short* __restrict__ hb,
                                              const float* __restrict__ W,
                                              float* __restrict__ parts) {
    __shared__ unsigned short As[256][40];   // [m][k], pad->40
    __shared__ unsigned int   Bs[128][18];   // [n][kpair] u32 = (bf16 k, bf16 k+1)
    int t = threadIdx.x;
    int wave = t >> 6, lane = t & 63;
    int wm = wave >> 1, wn = wave & 1;       // 4 M-waves x 2 N-waves
    int n0 = blockIdx.x * 128;
    int s  = blockIdx.y;
    int kbase = s * 2048;
    const int l15 = lane & 15, lk = lane >> 4;

    floatx4 acc[4][4];
    #pragma unroll
    for (int i = 0; i < 4; ++i)
        #pragma unroll
        for (int j = 0; j < 4; ++j)
            acc[i][j] = (floatx4)(0.f);

    int arow = t >> 1, ahalf = t & 1;
    int bkp = t & 15;        // k-pair 0..15 (fast index -> coalesced rows)
    int bng = t >> 4;        // col-group 0..31 (4 cols each)

    for (int kt = 0; kt < 2048; kt += 32) {
        int k0 = kbase + kt;
        __syncthreads();
        {   // stage A: 256x32 bf16
            const uint4* gp = (const uint4*)(hb + (size_t)arow * KDIM + k0 + ahalf * 16);
            uint4 v0 = gp[0], v1 = gp[1];
            *(uint4*)&As[arow][ahalf * 16]     = v0;
            *(uint4*)&As[arow][ahalf * 16 + 8] = v1;
        }
        {   // stage B: W[k0+2*bkp .. +1][n0 + bng*4 .. +3] -> bf16 pairs
            const float* wp = W + (size_t)(k0 + 2 * bkp) * 4096 + n0 + bng * 4;
            float4 r0 = *(const float4*)wp;
            float4 r1 = *(const float4*)(wp + 4096);
            Bs[bng * 4 + 0][bkp] = packbf2(r0.x, r1.x);
            Bs[bng * 4 + 1][bkp] = packbf2(r0.y, r1.y);
            Bs[bng * 4 + 2][bkp] = packbf2(r0.z, r1.z);
            Bs[bng * 4 + 3][bkp] = packbf2(r0.w, r1.w);
        }
        __syncthreads();
        short8 a[4], b[4];
        #pragma unroll
        for (int mi = 0; mi < 4; ++mi)
            a[mi] = *(const short8*)&As[wm * 64 + mi * 16 + l15][lk * 8];
        #pragma unroll
        for (int ni = 0; ni < 4; ++ni) {
            int nr = wn * 64 + ni * 16 + l15;
            union { uint2 u[2]; short8 v; } bb;
            bb.u[0] = *(const uint2*)&Bs[nr][lk * 4];
            bb.u[1] = *(const uint2*)&Bs[nr][lk * 4 + 2];
            b[ni] = bb.v;
        }
        #pragma unroll
        for (int mi = 0; mi < 4; ++mi)
            #pragma unroll
            for (int ni = 0; ni < 4; ++ni)
                acc[mi][ni] = __builtin_amdgcn_mfma_f32_16x16x32_bf16(a[mi], b[ni], acc[mi][ni], 0, 0, 0);
    }

    float* dst = parts + (size_t)s * (256 * 4096);
    #pragma unroll
    for (int mi = 0; mi < 4; ++mi) {
        #pragma unroll
        for (int ni = 0; ni < 4; ++ni) {
            int col = n0 + wn * 64 + ni * 16 + l15;
            #pragma unroll
            for (int r = 0; r < 4; ++r) {
                int row = wm * 64 + mi * 16 + lk * 4 + r;
                dst[(size_t)row * 4096 + col] = acc[mi][ni][r];
            }
        }
    }
}

// ---- reduce partials + bias -> d_out ---------------------------------------
__global__ __launch_bounds__(256) void k_reduce(const float* __restrict__ parts,
                                                const float* __restrict__ linb,
                                                float* __restrict__ out) {
    int idx = blockIdx.x * 256 + threadIdx.x;
    float v = linb[idx & 4095];
    #pragma unroll
    for (int s = 0; s < 8; ++s) v += parts[(size_t)s * (256 * 4096) + idx];
    out[idx] = v;
}

extern "C" void kernel_launch(void* const* d_in, const int* in_sizes, int n_in,
                              void* d_out, int out_size, void* d_ws, size_t ws_size,
                              hipStream_t stream) {
    (void)in_sizes; (void)n_in; (void)out_size; (void)ws_size;
    const float* x   = (const float*)d_in[0];
    const int*   ei  = (const int*)d_in[1];
    const float* ea  = (const float*)d_in[2];
    /* d_in[3] = batch (unused, fixed layout) */
    const float* Wl  = (const float*)d_in[4];
    const float* Wr  = (const float*)d_in[5];
    const float* We  = (const float*)d_in[6];
    const float* att = (const float*)d_in[7];
    const float* bg  = (const float*)d_in[8];
    const float* W   = (const float*)d_in[9];
    const float* lb  = (const float*)d_in[10];
    float* out = (float*)d_out;

    char* p = (char*)d_ws;
    float* xl           = (float*)p;          p += 16777216;           // 16384x256 f32
    float* xr           = (float*)p;          p += 16777216;
    unsigned short* hb  = (unsigned short*)p; p += 8388608;            // 16384x256 bf16
    float* parts        = (float*)p;          p += 33554432;           // 8x256x4096 f32
    float* eapart       = (float*)p;          p += 16384;              // 256x16
    float* eeself       = (float*)p;          p += 1024;               // 256

    k_ea_part  <<<256,  256, 0, stream>>>(ea, eapart);
    k_ea_finish<<<1,    256, 0, stream>>>(eapart, We, eeself);
    k_xlr      <<<1024, 256, 0, stream>>>(x, Wl, Wr, xl, xr);
    k_attn     <<<1024, 256, 0, stream>>>(ei, ea, eeself, att, We, xl, xr, bg, hb);
    k_gemm     <<<dim3(32, 8), 512, 0, stream>>>(hb, W, parts);
    k_reduce   <<<4096, 256, 0, stream>>>(parts, lb, out);
}

// Round 4
// 209.959 us; speedup vs baseline: 2.2276x; 1.2573x over previous
//
#include <hip/hip_runtime.h>
#include <hip/hip_bf16.h>

// Problem constants (fixed by reference)
#define N_NODES   16384
#define DEG       16
#define EDGES     262144          // N_NODES*DEG
#define HC        256             // HEADS*OUT_C
#define KDIM      16384           // 64 nodes * 256 feat
#define NEG_SLOPE 0.2f

typedef __attribute__((ext_vector_type(8))) short short8;   // 8 bf16
typedef __attribute__((ext_vector_type(4))) float floatx4;

static __device__ __forceinline__ unsigned short f2bf(float f) {
    union { __hip_bfloat16 h; unsigned short u; } c;
    c.h = __float2bfloat16(f);          // RNE
    return c.u;
}
static __device__ __forceinline__ unsigned int packbf2(float lo, float hi) {
    union { __hip_bfloat162 h2; unsigned int u; } c;
    c.h2 = __float22bfloat162_rn(make_float2(lo, hi));   // compiler -> v_cvt_pk_bf16_f32
    return c.u;
}

// ---- mean(edge_attr) partial sums: 256 blocks x 1024 rows -----------------
__global__ __launch_bounds__(256) void k_ea_part(const float* __restrict__ ea,
                                                 float* __restrict__ part) {
    __shared__ float s[256];
    int b = blockIdx.x, t = threadIdx.x;
    int col = t & 15, r0 = t >> 4;
    const float* base = ea + (size_t)b * 1024 * 16;
    float acc = 0.f;
    for (int r = r0; r < 1024; r += 16) acc += base[r * 16 + col];
    s[t] = acc; __syncthreads();
    for (int off = 128; off >= 16; off >>= 1) {
        if (t < off) s[t] += s[t + off];
        __syncthreads();
    }
    if (t < 16) part[b * 16 + t] = s[t];
}

// ---- finish mean + ee_self = mean_ea @ W_e ---------------------------------
__global__ __launch_bounds__(256) void k_ea_finish(const float* __restrict__ part,
                                                   const float* __restrict__ We,
                                                   float* __restrict__ eeself) {
    __shared__ float mean[16];
    int t = threadIdx.x;
    if (t < 16) {
        float a = 0.f;
        for (int b = 0; b < 256; ++b) a += part[b * 16 + t];
        mean[t] = a * (1.f / (float)EDGES);
    }
    __syncthreads();
    float acc = 0.f;
    #pragma unroll
    for (int d = 0; d < 16; ++d) acc += mean[d] * We[d * 256 + t];
    eeself[t] = acc;
}

// ---- xl|xr via MFMA: (16384 x 128) @ (128 x 512) ---------------------------
// grid (256, 4): m-tile 64 nodes, n-tile 128 of [Wl(256) | Wr(256)]
__global__ __launch_bounds__(256) void k_xlr2(const float* __restrict__ x,
                                              const float* __restrict__ Wl,
                                              const float* __restrict__ Wr,
                                              float* __restrict__ xl,
                                              float* __restrict__ xr) {
    __shared__ unsigned short As[64][40];   // [row][k] bf16, 80B rows (16B aligned)
    __shared__ unsigned int   Bs[128][18];  // [col][kpair]
    unsigned int* As32 = (unsigned int*)&As[0][0];

    int t = threadIdx.x;
    int wave = t >> 6, lane = t & 63;
    int l15 = lane & 15, lk = lane >> 4;
    int wm = wave >> 1, wn = wave & 1;
    int m0 = blockIdx.x * 64;
    int n0 = blockIdx.y * 128;
    const float* Wsel = (n0 < 256) ? Wl : Wr;
    int bc = n0 & 255;

    floatx4 acc[2][4];
    #pragma unroll
    for (int i = 0; i < 2; ++i)
        #pragma unroll
        for (int j = 0; j < 4; ++j)
            acc[i][j] = (floatx4)(0.f);

    int ar = t >> 2, ac = t & 3;       // A: row, 8-float chunk
    int bkp = t >> 4, bcc = t & 15;    // B: k-pair, 8-col chunk

    for (int k0 = 0; k0 < 128; k0 += 32) {
        __syncthreads();
        {   // stage A: x[m0+r][k0 + ac*8 .. +7] -> bf16
            const float* gp = x + (size_t)(m0 + ar) * 128 + k0 + ac * 8;
            float4 v0 = *(const float4*)gp;
            float4 v1 = *(const float4*)(gp + 4);
            As32[ar * 20 + ac * 4 + 0] = packbf2(v0.x, v0.y);
            As32[ar * 20 + ac * 4 + 1] = packbf2(v0.z, v0.w);
            As32[ar * 20 + ac * 4 + 2] = packbf2(v1.x, v1.y);
            As32[ar * 20 + ac * 4 + 3] = packbf2(v1.z, v1.w);
        }
        {   // stage B: Wsel rows k0+2bkp, +1; cols bc + bcc*8 .. +7
            const float* wp = Wsel + (size_t)(k0 + 2 * bkp) * 256 + bc + bcc * 8;
            float4 r0a = *(const float4*)wp;
            float4 r0b = *(const float4*)(wp + 4);
            float4 r1a = *(const float4*)(wp + 256);
            float4 r1b = *(const float4*)(wp + 260);
            Bs[bcc * 8 + 0][bkp] = packbf2(r0a.x, r1a.x);
            Bs[bcc * 8 + 1][bkp] = packbf2(r0a.y, r1a.y);
            Bs[bcc * 8 + 2][bkp] = packbf2(r0a.z, r1a.z);
            Bs[bcc * 8 + 3][bkp] = packbf2(r0a.w, r1a.w);
            Bs[bcc * 8 + 4][bkp] = packbf2(r0b.x, r1b.x);
            Bs[bcc * 8 + 5][bkp] = packbf2(r0b.y, r1b.y);
            Bs[bcc * 8 + 6][bkp] = packbf2(r0b.z, r1b.z);
            Bs[bcc * 8 + 7][bkp] = packbf2(r0b.w, r1b.w);
        }
        __syncthreads();
        short8 a[2], b[4];
        #pragma unroll
        for (int mi = 0; mi < 2; ++mi)
            a[mi] = *(const short8*)&As[wm * 32 + mi * 16 + l15][lk * 8];
        #pragma unroll
        for (int ni = 0; ni < 4; ++ni) {
            int nr = wn * 64 + ni * 16 + l15;
            union { uint2 u[2]; short8 v; } bb;
            bb.u[0] = *(const uint2*)&Bs[nr][lk * 4];
            bb.u[1] = *(const uint2*)&Bs[nr][lk * 4 + 2];
            b[ni] = bb.v;
        }
        #pragma unroll
        for (int mi = 0; mi < 2; ++mi)
            #pragma unroll
            for (int ni = 0; ni < 4; ++ni)
                acc[mi][ni] = __builtin_amdgcn_mfma_f32_16x16x32_bf16(a[mi], b[ni], acc[mi][ni], 0, 0, 0);
    }

    #pragma unroll
    for (int mi = 0; mi < 2; ++mi) {
        #pragma unroll
        for (int ni = 0; ni < 4; ++ni) {
            int n = n0 + wn * 64 + ni * 16 + l15;
            #pragma unroll
            for (int r = 0; r < 4; ++r) {
                int node = m0 + wm * 32 + mi * 16 + lk * 4 + r;
                if (n0 < 256) xl[(size_t)node * 256 + n]         = acc[mi][ni][r];
                else          xr[(size_t)node * 256 + (n - 256)] = acc[mi][ni][r];
            }
        }
    }
}

// ---- fused GAT attention: MFMA ee + in-layout logits + softmax + agg -------
// grid: 1024 blocks = (graph g, head h); block = 256 threads = 4 waves
__global__ __launch_bounds__(256) void k_attn(const int* __restrict__ ei,
                                              const float* __restrict__ ea,
                                              const float* __restrict__ eeself,
                                              const float* __restrict__ att,
                                              const float* __restrict__ We,
                                              const float* __restrict__ xl,
                                              const float* __restrict__ xr,
                                              const float* __restrict__ bg,
                                              unsigned short* __restrict__ hb) {
    __shared__ float xlS[64][65];
    __shared__ float xrS[64][65];
    __shared__ float lgS[1088];      // 1024 edge logits + 64 self
    __shared__ int   srcS[1024];

    int t = threadIdx.x;
    int g = blockIdx.x >> 2, h = blockIdx.x & 3;
    int hc0 = h * 64;

    {   // stage xl/xr head slices: 64 nodes x 64 feats
        int n = t >> 2, q4 = t & 3;
        const float* xlp = xl + ((size_t)(g * 64 + n)) * 256 + hc0 + q4 * 16;
        const float* xrp = xr + ((size_t)(g * 64 + n)) * 256 + hc0 + q4 * 16;
        #pragma unroll
        for (int i = 0; i < 4; ++i) {
            *(float4*)&xlS[n][q4 * 16 + i * 4] = *(const float4*)(xlp + i * 4);
            *(float4*)&xrS[n][q4 * 16 + i * 4] = *(const float4*)(xrp + i * 4);
        }
    }
    {   // stage local src indices for all 1024 edges
        int4 v = *(const int4*)(ei + (size_t)g * 1024 + t * 4);
        srcS[t * 4 + 0] = v.x & 63;
        srcS[t * 4 + 1] = v.y & 63;
        srcS[t * 4 + 2] = v.z & 63;
        srcS[t * 4 + 3] = v.w & 63;
    }

    int wave = t >> 6, lane = t & 63;
    int q = lane >> 4, l15 = lane & 15;

    // B-frags: We head-slice held in registers for the whole block.
    short8 wf[4];
    float  attv[4];
    #pragma unroll
    for (int nt = 0; nt < 4; ++nt) {
        attv[nt] = att[hc0 + nt * 16 + l15];
        if (q < 2) {
            const float* wp = We + (size_t)(q * 8) * 256 + hc0 + nt * 16 + l15;
            float w0 = wp[0*256], w1 = wp[1*256], w2 = wp[2*256], w3 = wp[3*256];
            float w4 = wp[4*256], w5 = wp[5*256], w6 = wp[6*256], w7 = wp[7*256];
            union { unsigned int u[4]; short8 v; } bb;
            bb.u[0] = packbf2(w0, w1);
            bb.u[1] = packbf2(w2, w3);
            bb.u[2] = packbf2(w4, w5);
            bb.u[3] = packbf2(w6, w7);
            wf[nt] = bb.v;
        } else {
            wf[nt] = (short8)0;
        }
    }
    __syncthreads();

    // ---- edge batches: 16 batches of 64 edges, waves independent ----
    for (int b = wave; b < 16; b += 4) {
        short8 af[4];
        #pragma unroll
        for (int mt = 0; mt < 4; ++mt) {
            if (q < 2) {
                const float* ep = ea + ((size_t)(g * 1024 + b * 64 + mt * 16 + l15)) * 16 + q * 8;
                float4 v0 = *(const float4*)ep;
                float4 v1 = *(const float4*)(ep + 4);
                union { unsigned int u[4]; short8 v; } bb;
                bb.u[0] = packbf2(v0.x, v0.y);
                bb.u[1] = packbf2(v0.z, v0.w);
                bb.u[2] = packbf2(v1.x, v1.y);
                bb.u[3] = packbf2(v1.z, v1.w);
                af[mt] = bb.v;
            } else {
                af[mt] = (short8)0;
            }
        }
        floatx4 acc[4][4];
        #pragma unroll
        for (int mt = 0; mt < 4; ++mt)
            #pragma unroll
            for (int nt = 0; nt < 4; ++nt)
                acc[mt][nt] = __builtin_amdgcn_mfma_f32_16x16x32_bf16(af[mt], wf[nt], (floatx4)(0.f), 0, 0, 0);

        int srcr[4][4];
        #pragma unroll
        for (int mt = 0; mt < 4; ++mt)
            #pragma unroll
            for (int r = 0; r < 4; ++r)
                srcr[mt][r] = srcS[b * 64 + mt * 16 + q * 4 + r];

        #pragma unroll
        for (int mt = 0; mt < 4; ++mt) {
            float lsum[4] = {0.f, 0.f, 0.f, 0.f};
            #pragma unroll
            for (int nt = 0; nt < 4; ++nt) {
                float xrv = xrS[b * 4 + mt][nt * 16 + l15];   // dst uniform per mt
                #pragma unroll
                for (int r = 0; r < 4; ++r) {
                    float f = acc[mt][nt][r] + xlS[srcr[mt][r]][nt * 16 + l15] + xrv;
                    f = fmaxf(f, NEG_SLOPE * f);              // leaky_relu
                    lsum[r] += f * attv[nt];
                }
            }
            #pragma unroll
            for (int r = 0; r < 4; ++r) {
                float v = lsum[r];
                v += __shfl_xor(v, 1);
                v += __shfl_xor(v, 2);
                v += __shfl_xor(v, 4);
                v += __shfl_xor(v, 8);
                if (l15 == 0) lgS[b * 64 + mt * 16 + q * 4 + r] = v;
            }
        }
    }

    // ---- self-loop batch ----
    {
        int n = wave * 16 + l15;
        float sum = 0.f;
        const float* eep = eeself + hc0 + q * 16;
        const float* ap  = att + hc0 + q * 16;
        #pragma unroll
        for (int i = 0; i < 4; ++i) {
            float4 ev = *(const float4*)(eep + i * 4);
            float4 av = *(const float4*)(ap + i * 4);
            #pragma unroll
            for (int j = 0; j < 4; ++j) {
                int c = q * 16 + i * 4 + j;
                float e = (j == 0) ? ev.x : (j == 1) ? ev.y : (j == 2) ? ev.z : ev.w;
                float a = (j == 0) ? av.x : (j == 1) ? av.y : (j == 2) ? av.z : av.w;
                float f = xlS[n][c] + xrS[n][c] + e;
                f = fmaxf(f, NEG_SLOPE * f);
                sum += f * a;
            }
        }
        sum += __shfl_xor(sum, 16);
        sum += __shfl_xor(sum, 32);
        if (q == 0) lgS[1024 + n] = sum;
    }
    __syncthreads();

    // ---- segment softmax per dst node (17 entries), fold 1/17 ----
    if (t < 64) {
        float lg[17];
        #pragma unroll
        for (int j = 0; j < 16; ++j) lg[j] = lgS[t * 16 + j];
        lg[16] = lgS[1024 + t];
        float m = lg[0];
        #pragma unroll
        for (int j = 1; j < 17; ++j) m = fmaxf(m, lg[j]);
        float ex[17], ssum = 0.f;
        #pragma unroll
        for (int j = 0; j < 17; ++j) { ex[j] = __expf(lg[j] - m); ssum += ex[j]; }
        float inv = 1.f / (17.f * ssum);
        #pragma unroll
        for (int j = 0; j < 16; ++j) lgS[t * 16 + j] = ex[j] * inv;
        lgS[1024 + t] = ex[16] * inv;
    }
    __syncthreads();

    // ---- aggregation: lane = feature c, 16 nodes per wave ----
    {
        int c = lane;
        float bgv = bg[hc0 + c];
        for (int n = wave * 16; n < wave * 16 + 16; ++n) {
            float a0 = lgS[1024 + n] * xlS[n][c];
            float a1 = 0.f;
            #pragma unroll
            for (int j = 0; j < 16; j += 2) {
                a0 += lgS[n * 16 + j]     * xlS[srcS[n * 16 + j]][c];
                a1 += lgS[n * 16 + j + 1] * xlS[srcS[n * 16 + j + 1]][c];
            }
            float val = a0 + a1 + bgv;
            hb[((size_t)(g * 64 + n)) * 256 + hc0 + c] = f2bf(val);
        }
    }
}

// ---- big GEMM v4: N-tile 64, 256 thr, A via global_load_lds ----------------
// (256 x 16384) bf16 @ W[16384 x 4096] -> partials[s][256][4096]
__global__ __launch_bounds__(256, 3) void k_gemm(const unsigned short* __restrict__ hb,
                                                 const float* __restrict__ W,
                                                 float* __restrict__ parts) {
    __shared__ unsigned short As[256][32];   // LINEAR (global_load_lds dest)
    __shared__ unsigned int   Bs[64][18];    // [n][kpair]
    int t = threadIdx.x;
    int wave = t >> 6, lane = t & 63;
    int l15 = lane & 15, lk = lane >> 4;
    int n0 = blockIdx.x * 64;
    int s  = blockIdx.y;
    int kbase = s * 2048;

    floatx4 acc[4][4];
    #pragma unroll
    for (int i = 0; i < 4; ++i)
        #pragma unroll
        for (int j = 0; j < 4; ++j)
            acc[i][j] = (floatx4)(0.f);

    int bkp = t >> 4;     // 0..15 row-pair
    int bc8 = t & 15;     // col chunk (4 cols)

    for (int kt = 0; kt < 2048; kt += 32) {
        int k0 = kbase + kt;
        __syncthreads();
        // stage A: wave w loads rows w*64 .. w*64+63, 16B per lane, linear LDS
        #pragma unroll
        for (int i = 0; i < 4; ++i) {
            int rbase = wave * 64 + i * 16;
            const unsigned short* gp = hb + (size_t)(rbase + (lane >> 2)) * KDIM + k0 + (lane & 3) * 8;
            __builtin_amdgcn_global_load_lds(
                (const __attribute__((address_space(1))) unsigned int*)gp,
                (__attribute__((address_space(3))) unsigned int*)&As[rbase][0],
                16, 0, 0);
        }
        {   // stage B: W rows k0+2bkp, +1; cols n0 + bc8*4 -> bf16 pairs
            const float* wp = W + (size_t)(k0 + 2 * bkp) * 4096 + n0 + bc8 * 4;
            float4 r0 = *(const float4*)wp;
            float4 r1 = *(const float4*)(wp + 4096);
            Bs[bc8 * 4 + 0][bkp] = packbf2(r0.x, r1.x);
            Bs[bc8 * 4 + 1][bkp] = packbf2(r0.y, r1.y);
            Bs[bc8 * 4 + 2][bkp] = packbf2(r0.z, r1.z);
            Bs[bc8 * 4 + 3][bkp] = packbf2(r0.w, r1.w);
        }
        __syncthreads();
        short8 a[4], b[4];
        #pragma unroll
        for (int mi = 0; mi < 4; ++mi)
            a[mi] = *(const short8*)&As[wave * 64 + mi * 16 + l15][lk * 8];
        #pragma unroll
        for (int ni = 0; ni < 4; ++ni) {
            int nr = ni * 16 + l15;
            union { uint2 u[2]; short8 v; } bb;
            bb.u[0] = *(const uint2*)&Bs[nr][lk * 4];
            bb.u[1] = *(const uint2*)&Bs[nr][lk * 4 + 2];
            b[ni] = bb.v;
        }
        #pragma unroll
        for (int mi = 0; mi < 4; ++mi)
            #pragma unroll
            for (int ni = 0; ni < 4; ++ni)
                acc[mi][ni] = __builtin_amdgcn_mfma_f32_16x16x32_bf16(a[mi], b[ni], acc[mi][ni], 0, 0, 0);
    }

    float* dst = parts + (size_t)s * (256 * 4096);
    #pragma unroll
    for (int mi = 0; mi < 4; ++mi) {
        #pragma unroll
        for (int ni = 0; ni < 4; ++ni) {
            int col = n0 + ni * 16 + l15;
            #pragma unroll
            for (int r = 0; r < 4; ++r) {
                int row = wave * 64 + mi * 16 + lk * 4 + r;
                dst[(size_t)row * 4096 + col] = acc[mi][ni][r];
            }
        }
    }
}

// ---- reduce partials + bias -> d_out ---------------------------------------
__global__ __launch_bounds__(256) void k_reduce(const float* __restrict__ parts,
                                                const float* __restrict__ linb,
                                                float* __restrict__ out) {
    int idx = blockIdx.x * 256 + threadIdx.x;
    float v = linb[idx & 4095];
    #pragma unroll
    for (int s = 0; s < 8; ++s) v += parts[(size_t)s * (256 * 4096) + idx];
    out[idx] = v;
}

extern "C" void kernel_launch(void* const* d_in, const int* in_sizes, int n_in,
                              void* d_out, int out_size, void* d_ws, size_t ws_size,
                              hipStream_t stream) {
    (void)in_sizes; (void)n_in; (void)out_size; (void)ws_size;
    const float* x   = (const float*)d_in[0];
    const int*   ei  = (const int*)d_in[1];
    const float* ea  = (const float*)d_in[2];
    /* d_in[3] = batch (unused, fixed layout) */
    const float* Wl  = (const float*)d_in[4];
    const float* Wr  = (const float*)d_in[5];
    const float* We  = (const float*)d_in[6];
    const float* att = (const float*)d_in[7];
    const float* bg  = (const float*)d_in[8];
    const float* W   = (const float*)d_in[9];
    const float* lb  = (const float*)d_in[10];
    float* out = (float*)d_out;

    char* p = (char*)d_ws;
    float* xl           = (float*)p;          p += 16777216;           // 16384x256 f32
    float* xr           = (float*)p;          p += 16777216;
    unsigned short* hb  = (unsigned short*)p; p += 8388608;            // 16384x256 bf16
    float* parts        = (float*)p;          p += 33554432;           // 8x256x4096 f32
    float* eapart       = (float*)p;          p += 16384;              // 256x16
    float* eeself       = (float*)p;          p += 1024;               // 256

    k_ea_part  <<<256,  256, 0, stream>>>(ea, eapart);
    k_ea_finish<<<1,    256, 0, stream>>>(eapart, We, eeself);
    k_xlr2     <<<dim3(256, 4), 256, 0, stream>>>(x, Wl, Wr, xl, xr);
    k_attn     <<<1024, 256, 0, stream>>>(ei, ea, eeself, att, We, xl, xr, bg, hb);
    k_gemm     <<<dim3(64, 8), 256, 0, stream>>>(hb, W, parts);
    k_reduce   <<<4096, 256, 0, stream>>>(parts, lb, out);
}